// Round 6
// baseline (519.182 us; speedup 1.0000x reference)
//
#include <hip/hip_runtime.h>

// LocalExpansion: out[b,h,(y,x),c,d] = in[b,h,(y+i-3,x+j-3),d], c = i*7+j,
// zero-filled outside the image. 462 MB write, 9.4 MB input.
//
// v13 = store-granularity probe (M1 vs M2 discriminator).
// History: kernel-side residual K = bench - ~292us poison fill is ~164-172us
// across FOUR structurally different kernels: v8 (flat, plain stores),
// v10 (nt stores), v11 (+XCD swizzle), v12 (LDS staging, HBM reads bounded
// to ~25 MB by construction). v12's neutrality KILLS all read-side theories.
// Remaining: M1 = stores sustain only ~2.8 TB/s because every variant wrote
// 16 B/thread/instr with 4 KB stride between a thread's stores (the 6.3 TB/s
// harness fill writes fat contiguous per-thread bursts); M2 = kernel already
// at ~80-90us floor and the residual is hidden harness restore dispatches.
//
// v13: each thread owns 4 CONSECUTIVE float4 = one aligned 64 B chunk.
//   q = global thread id; idx4 = 4q+u, u=0..3 -> rem = idx4>>4 = q>>2 is
//   u-invariant: all 4 f4 share one (bh, n, c) cell, d4 = 4(q&3)+u.
//   One index/div chain (was 4), one 64 B load, one bounds-select,
//   one 64 B contiguous store per thread; each wave stores 4 KB contiguous.
// Plain (non-nt) stores to mimic the fill exactly (v10 showed nt neutral).
// Prediction: M1 -> bench ~380-400us; neutral -> M2 accepted, roofline.

#define KH 7
#define KW 7
#define HEIGHT 48
#define WIDTH 48
#define DDIM 64
#define NPIX (HEIGHT * WIDTH)   // 2304
#define KK (KH * KW)            // 49

typedef __attribute__((ext_vector_type(4))) float f4;

__global__ __launch_bounds__(256) void local_expansion_kernel(
    const float* __restrict__ in, float* __restrict__ out) {
    int q = blockIdx.x * 256 + threadIdx.x;   // global thread id

    // All 4 of this thread's output f4 (idx4 = 4q+u) share one cell:
    int rem  = q >> 2;          // = (bh*NPIX + n)*KK + c
    int d4b  = (q & 3) * 4;     // base d4; chunk covers d4b..d4b+3
    int c    = rem % KK;
    int rem2 = rem / KK;
    int n    = rem2 % NPIX;
    int bh   = rem2 / NPIX;

    int y = n / WIDTH;
    int x = n - y * WIDTH;
    int i = c / KW;
    int j = c - i * KW;

    int sy = y + i - (KH - 1) / 2;
    int sx = x + j - (KW - 1) / 2;

    bool inb = ((unsigned)sy < (unsigned)HEIGHT) & ((unsigned)sx < (unsigned)WIDTH);

    // Branchless: clamp to a valid address, load 64 B, select.
    int syc = min(max(sy, 0), HEIGHT - 1);
    int sxc = min(max(sx, 0), WIDTH - 1);
    const f4* src = (const f4*)in +
                    ((size_t)(bh * NPIX + syc * WIDTH + sxc) * (DDIM / 4) + d4b);

    f4 t0 = src[0];
    f4 t1 = src[1];
    f4 t2 = src[2];
    f4 t3 = src[3];
    f4 z  = (f4)(0.f);

    // One aligned 64 B contiguous store per thread; 4 KB contiguous per wave.
    f4* dst = (f4*)out + (size_t)q * 4;
    dst[0] = inb ? t0 : z;
    dst[1] = inb ? t1 : z;
    dst[2] = inb ? t2 : z;
    dst[3] = inb ? t3 : z;
}

extern "C" void kernel_launch(void* const* d_in, const int* in_sizes, int n_in,
                              void* d_out, int out_size, void* d_ws, size_t ws_size,
                              hipStream_t stream) {
    const float* x = (const float*)d_in[0];
    float* out = (float*)d_out;

    // out_size = 115,605,504 floats -> 28,901,376 float4s; 4 per thread,
    // 256 threads/block -> 28,224 blocks exact.
    int total4 = out_size / 4;
    int blocks = total4 / (256 * 4);
    local_expansion_kernel<<<dim3(blocks), 256, 0, stream>>>(x, out);
}

// Round 7
// 456.542 us; speedup vs baseline: 1.1372x; 1.1372x over previous
//
#include <hip/hip_runtime.h>

// LocalExpansion: out[b,h,(y,x),c,d] = in[b,h,(y+i-3,x+j-3),d], c = i*7+j,
// zero-filled outside the image. 462 MB write, 9.4 MB input (cache-resident).
//
// v14 = revert to v10 (best measured: 456.5 us), replacing the regressed v13.
//
// FINAL ACCOUNTING (rounds 0-6): bench dur ~460 us decomposes as
//   ~292 us  harness poison fill (1.85 GB @ 6.33 TB/s, visible in rocprof)
//   ~70-90us ~35-45 tiny hipMemsetAsync/restore reset dispatches (fill _ord
//            spacing 36-46 proves their count; ~2 us launch latency each)
//   ~85-95us this kernel vs the 73 us pure-write floor (462 MB @ 6.3 TB/s).
// Evidence: four structurally different kernels (v8 flat / v10 nt / v11
// XCD-swizzle / v12 LDS-staged with HBM reads bounded to ~25 MB) all landed
// 456-468 us -> read side never mattered, kernel near floor all along.
// v13 (64 B/thread chunks) REGRESSED +55 us: widest store is dwordx4, so
// chunking emits 4x strided 16 B partial-line stores -> read-for-ownership
// (~462 MB extra reads = the +55 us). Proves this kernel's store pattern
// (16 B/lane, 1 KB/wave-instruction, full lines per instruction) is
// ISA-optimal on gfx950.
//
// Structure: 4-deep ILP per wave, block-contiguous unroll - thread t of
// block b handles idx4 = b*1024 + u*256 + t. All 4 branchless loads
// (clamped addr + select) issue before the first store; every store is
// 256-lane contiguous; each block writes one 16 KB contiguous span;
// non-temporal stores (write-once output, keeps L2 for the input).

#define KH 7
#define KW 7
#define HEIGHT 48
#define WIDTH 48
#define DDIM 64
#define NPIX (HEIGHT * WIDTH)   // 2304
#define KK (KH * KW)            // 49
#define UNROLL 4

typedef __attribute__((ext_vector_type(4))) float nt_float4;

__global__ __launch_bounds__(256) void local_expansion_kernel(
    const float* __restrict__ in, float* __restrict__ out) {
    int base4 = blockIdx.x * (256 * UNROLL) + threadIdx.x;

    nt_float4 v[UNROLL];

#pragma unroll
    for (int u = 0; u < UNROLL; ++u) {
        int idx4 = base4 + u * 256;

        // idx4 = ((bh*NPIX + n)*KK + c)*16 + d4
        int d4   = idx4 & 15;
        int rem  = idx4 >> 4;
        int c    = rem % KK;
        int rem2 = rem / KK;
        int n    = rem2 % NPIX;
        int bh   = rem2 / NPIX;

        int y = n / WIDTH;
        int x = n - y * WIDTH;
        int i = c / KW;
        int j = c - i * KW;

        int sy = y + i - (KH - 1) / 2;
        int sx = x + j - (KW - 1) / 2;

        bool inb = ((unsigned)sy < (unsigned)HEIGHT) & ((unsigned)sx < (unsigned)WIDTH);

        // Branchless: clamp to a valid address, load unconditionally, select.
        int syc = min(max(sy, 0), HEIGHT - 1);
        int sxc = min(max(sx, 0), WIDTH - 1);
        int in4 = (bh * NPIX + syc * WIDTH + sxc) * (DDIM / 4) + d4;

        nt_float4 t = ((const nt_float4*)in)[in4];
        nt_float4 z = (nt_float4)(0.f);
        v[u] = inb ? t : z;
    }

#pragma unroll
    for (int u = 0; u < UNROLL; ++u) {
        // Output is write-once, never re-read: non-temporal store keeps the
        // 462 MB stream evict-first in L2 so the input stays cache-resident.
        __builtin_nontemporal_store(v[u], ((nt_float4*)out) + base4 + u * 256);
    }
}

extern "C" void kernel_launch(void* const* d_in, const int* in_sizes, int n_in,
                              void* d_out, int out_size, void* d_ws, size_t ws_size,
                              hipStream_t stream) {
    const float* x = (const float*)d_in[0];
    float* out = (float*)d_out;

    // out_size = 115,605,504 floats -> 28,901,376 float4s; /(256*4) = 28,224 exact
    int total4 = out_size / 4;
    int blocks = total4 / (256 * UNROLL);
    local_expansion_kernel<<<dim3(blocks), 256, 0, stream>>>(x, out);
}